// Round 10
// baseline (193.515 us; speedup 1.0000x reference)
//
#include <hip/hip_runtime.h>
#include <math.h>

#define N_NODES 100000
#define N_EDGES 1600000
#define F0 32
#define F1 16
#define F2 8
#define NCLS 6
#define NGRAPH 64

#define BSH  8         // bucket = 256 nodes (power of 2 -> exact split)
#define BSZ  256       // nodes per bucket
#define NBUK 391       // ceil(100000/256)
#define CAPB 4608      // edge cap per bucket region (mean 4092, sigma 64 -> +8 sigma)
#define EPB  4093      // edges per xpart chunk: ceil(1600000/391)
#define NPW  257       // np_g stride per bucket

// ========== kernel 1: fused node-transform (x@W1a) + edge partition ==========
__global__ __launch_bounds__(256) void xpart_k(
    const float* __restrict__ x, const float* __restrict__ W1a,
    float* __restrict__ xw1, const int* __restrict__ ei,
    int* __restrict__ gcursor, int* __restrict__ pairs) {
    __shared__ float sW[F0 * F1];
    __shared__ int hist[512];
    __shared__ int cur[512];
    __shared__ int sdst[EPB];
    int t = threadIdx.x, c = blockIdx.x;
    for (int i = t; i < F0 * F1; i += 256) sW[i] = W1a[i];
    hist[t] = 0; hist[t + 256] = 0;
    __syncthreads();

    // --- stage dst + chunk histogram ---
    int base = c * EPB, eend = min(base + EPB, N_EDGES);
    for (int i = base + t; i < eend; i += 256) {
        int d = ei[N_EDGES + i];
        sdst[i - base] = d;
        atomicAdd(&hist[d >> BSH], 1);
    }

    // --- node projection (independent work, overlaps hist latency) ---
    int n = c * 256 + t;
    if (n < N_NODES) {
        const float4* xp = reinterpret_cast<const float4*>(x) + n * (F0 / 4);
        float xi[F0];
#pragma unroll
        for (int q = 0; q < F0 / 4; q++) {
            float4 v = xp[q];
            xi[4*q] = v.x; xi[4*q+1] = v.y; xi[4*q+2] = v.z; xi[4*q+3] = v.w;
        }
        float o[F1];
#pragma unroll
        for (int j = 0; j < F1; j++) {
            float s = 0.0f;
#pragma unroll
            for (int k = 0; k < F0; k++) s += xi[k] * sW[k * F1 + j];
            o[j] = s;
        }
        float4* op = reinterpret_cast<float4*>(xw1) + n * (F1 / 4);
        op[0] = make_float4(o[0],  o[1],  o[2],  o[3]);
        op[1] = make_float4(o[4],  o[5],  o[6],  o[7]);
        op[2] = make_float4(o[8],  o[9],  o[10], o[11]);
        op[3] = make_float4(o[12], o[13], o[14], o[15]);
    }
    __syncthreads();

    // --- reserve contiguous sub-range per bucket (strided: NBUK > 256) ---
    for (int b = t; b < 512; b += 256) {
        int cnt = (b < NBUK) ? hist[b] : 0;
        cur[b] = b * CAPB + (cnt ? atomicAdd(&gcursor[b], cnt) : 0);
    }
    __syncthreads();

    // --- scatter packed (dl<<17 | src) into bucket regions (guarded) ---
    for (int i = base + t; i < eend; i += 256) {
        int s = ei[i];
        int d = sdst[i - base];
        int b = d >> BSH;
        int pos = atomicAdd(&cur[b], 1);
        if (pos < (b + 1) * CAPB)                 // overflow guard (~never taken)
            pairs[pos] = ((d & (BSZ - 1)) << 17) | s;
    }
}

#define ACC16(P) { float4 q0 = (P)[0], q1 = (P)[1], q2 = (P)[2], q3 = (P)[3]; \
    acc[0] += q0.x;  acc[1] += q0.y;  acc[2]  += q0.z;  acc[3]  += q0.w;      \
    acc[4] += q1.x;  acc[5] += q1.y;  acc[6]  += q1.z;  acc[7]  += q1.w;      \
    acc[8] += q2.x;  acc[9] += q2.y;  acc[10] += q2.z;  acc[11] += q2.w;      \
    acc[12] += q3.x; acc[13] += q3.y; acc[14] += q3.z;  acc[15] += q3.w; }

// ===== kernel 2: per-bucket counting sort (LDS) + gin1 straight from LDS =====
__global__ __launch_bounds__(256) void sortgin1_k(
    const float* __restrict__ xw1, const int* __restrict__ pairs,
    const int* __restrict__ gcursor,
    const float* __restrict__ b1a, const float* __restrict__ W1b,
    const float* __restrict__ b1b, const float* __restrict__ W2a,
    float* __restrict__ h1w, int* __restrict__ srcs,
    int* __restrict__ np_g) {
    __shared__ int hist[256];
    __shared__ int sbuf[2][256];
    __shared__ int cur[256];
    __shared__ int np[BSZ + 1];
    __shared__ int srcs_l[CAPB];
    __shared__ float sW1b[F1 * F1];
    __shared__ float sW2a[F1 * F2];
    __shared__ float sb1a[F1], sb1b[F1];
    int t = threadIdx.x, b = blockIdx.x;
    if (t < F1 * F1) sW1b[t] = W1b[t];
    if (t < F1 * F2) sW2a[t] = W2a[t];
    if (t < F1) { sb1a[t] = b1a[t]; sb1b[t] = b1b[t]; }
    hist[t] = 0;
    __syncthreads();

    int cnt = min(gcursor[b], CAPB);
    int pb = b * CAPB;
    for (int i = t; i < cnt; i += 256)
        atomicAdd(&hist[pairs[pb + i] >> 17], 1);
    __syncthreads();
    sbuf[0][t] = hist[t];
    __syncthreads();
    int cb = 0;
    for (int off = 1; off < 256; off <<= 1) {
        int v = sbuf[cb][t];
        if (t >= off) v += sbuf[cb][t - off];
        sbuf[cb ^ 1][t] = v;
        cb ^= 1;
        __syncthreads();
    }
    int excl = sbuf[cb][t] - hist[t];
    np[t] = excl;
    cur[t] = excl;
    if (t == 0) np[BSZ] = cnt;
    __syncthreads();
    for (int i = t; i < cnt; i += 256) {
        int p = pairs[pb + i];
        int pos = atomicAdd(&cur[p >> 17], 1);
        int s = p & 0x1FFFF;
        srcs_l[pos] = s;             // consumed by gin1 below (no global round-trip)
        srcs[pb + pos] = s;          // persisted for gin2 (bucket-local write)
    }
    // compact per-node offsets for gin2 (bucket-relative)
    np_g[b * NPW + t] = np[t];
    if (t == 0) np_g[b * NPW + BSZ] = np[BSZ];
    __syncthreads();

    int n = b * BSZ + t;
    if (n < N_NODES) {
        float acc[F1];
#pragma unroll
        for (int k = 0; k < F1; k++) acc[k] = 0.0f;
        const float4* X = reinterpret_cast<const float4*>(xw1);
        int e = np[t], end = np[t + 1];
        for (; e + 4 <= end; e += 4) {
            const float4* p0 = X + srcs_l[e + 0] * 4;
            const float4* p1 = X + srcs_l[e + 1] * 4;
            const float4* p2 = X + srcs_l[e + 2] * 4;
            const float4* p3 = X + srcs_l[e + 3] * 4;
            ACC16(p0); ACC16(p1); ACC16(p2); ACC16(p3);
        }
        for (; e < end; e++) { const float4* p0 = X + srcs_l[e] * 4; ACC16(p0); }
        { const float4* pn = X + n * 4; ACC16(pn); }   // self term

        float u[F1];
#pragma unroll
        for (int k = 0; k < F1; k++) u[k] = fmaxf(acc[k] + sb1a[k], 0.0f);
        float h[F1];
#pragma unroll
        for (int j = 0; j < F1; j++) {
            float s = sb1b[j];
#pragma unroll
            for (int k = 0; k < F1; k++) s += u[k] * sW1b[k * F1 + j];
            h[j] = fmaxf(s, 0.0f);          // relu∘relu = relu
        }
        float o[F2];
#pragma unroll
        for (int j = 0; j < F2; j++) {
            float s = 0.0f;
#pragma unroll
            for (int k = 0; k < F1; k++) s += h[k] * sW2a[k * F2 + j];
            o[j] = s;
        }
        float4* hp = reinterpret_cast<float4*>(h1w) + n * 2;
        hp[0] = make_float4(o[0], o[1], o[2], o[3]);
        hp[1] = make_float4(o[4], o[5], o[6], o[7]);
    }
}

#define ACC8(P) { float4 q0 = (P)[0], q1 = (P)[1];                        \
    acc[0] += q0.x; acc[1] += q0.y; acc[2] += q0.z; acc[3] += q0.w;       \
    acc[4] += q1.x; acc[5] += q1.y; acc[6] += q1.z; acc[7] += q1.w; }

// == kernel 3: layer-2 gather + MLP2 + mean-pool + LAST-BLOCK final softmax ==
__global__ __launch_bounds__(256) void gin2pf_k(
    const float* __restrict__ h1w, const int* __restrict__ np_g,
    const int* __restrict__ srcs, const float* __restrict__ b2a,
    const float* __restrict__ W2b, const float* __restrict__ b2b,
    const int* __restrict__ batch, float* __restrict__ gsum,
    float* __restrict__ gcnt, int* __restrict__ ticket,
    const float* __restrict__ Wfc, const float* __restrict__ bfc,
    float* __restrict__ out) {
    __shared__ float sW2b[F2 * F2];
    __shared__ float sb2a[F2];
    __shared__ float sb2b[F2];
    __shared__ float ls[NGRAPH * F2];   // 512 > blockDim -> strided loops (r5 lesson)
    __shared__ float lc[NGRAPH];
    __shared__ int amLast;
    int t = threadIdx.x, b = blockIdx.x;
    if (t < F2 * F2) sW2b[t] = W2b[t];
    if (t < F2) { sb2a[t] = b2a[t]; sb2b[t] = b2b[t]; }
    for (int i = t; i < NGRAPH * F2; i += 256) ls[i] = 0.0f;
    if (t < NGRAPH) lc[t] = 0.0f;
    __syncthreads();

    int n = b * BSZ + t;
    if (n < N_NODES) {
        float acc[F2];
#pragma unroll
        for (int k = 0; k < F2; k++) acc[k] = 0.0f;
        const float4* H = reinterpret_cast<const float4*>(h1w);
        int pb = b * CAPB;
        int e   = pb + np_g[b * NPW + t];
        int end = pb + np_g[b * NPW + t + 1];
        for (; e + 4 <= end; e += 4) {
            const float4* p0 = H + srcs[e + 0] * 2;
            const float4* p1 = H + srcs[e + 1] * 2;
            const float4* p2 = H + srcs[e + 2] * 2;
            const float4* p3 = H + srcs[e + 3] * 2;
            ACC8(p0); ACC8(p1); ACC8(p2); ACC8(p3);
        }
        for (; e < end; e++) { const float4* p0 = H + srcs[e] * 2; ACC8(p0); }
        { const float4* pn = H + n * 2; ACC8(pn); }    // self term

        float u[F2];
#pragma unroll
        for (int k = 0; k < F2; k++) u[k] = fmaxf(acc[k] + sb2a[k], 0.0f);
        float v[F2];
#pragma unroll
        for (int j = 0; j < F2; j++) {
            float s = sb2b[j];
#pragma unroll
            for (int k = 0; k < F2; k++) s += u[k] * sW2b[k * F2 + j];
            v[j] = fmaxf(s, 0.0f);
        }
        int g = batch[n];
#pragma unroll
        for (int j = 0; j < F2; j++) atomicAdd(&ls[g * F2 + j], v[j]);
        atomicAdd(&lc[g], 1.0f);
    }
    __syncthreads();
    for (int i = t; i < NGRAPH * F2; i += 256)
        if (ls[i] != 0.0f) atomicAdd(&gsum[i], ls[i]);
    if (t < NGRAPH && lc[t] != 0.0f) atomicAdd(&gcnt[t], lc[t]);

    // __syncthreads on CDNA drains vmcnt -> all this block's atomics complete
    __syncthreads();
    __threadfence();
    if (t == 0) amLast = (atomicAdd(ticket, 1) == NBUK - 1);
    __syncthreads();

    if (amLast && t < NGRAPH) {
        int g = t;
        // coherent reads via atomic fetch-add 0 (device-scope point)
        float cnt = fmaxf(atomicAdd(&gcnt[g], 0.0f), 1.0f);
        float p[F2];
#pragma unroll
        for (int f = 0; f < F2; f++)
            p[f] = atomicAdd(&gsum[g * F2 + f], 0.0f) / cnt;
        float l[NCLS];
#pragma unroll
        for (int c = 0; c < NCLS; c++) {
            float s = bfc[c];
#pragma unroll
            for (int f = 0; f < F2; f++) s += p[f] * Wfc[f * NCLS + c];
            l[c] = s;
        }
        float m = -INFINITY;
#pragma unroll
        for (int c = 0; c < NCLS; c++) m = fmaxf(m, l[c]);
        float s = 0.0f;
#pragma unroll
        for (int c = 0; c < NCLS; c++) s += expf(l[c] - m);
        float lse = m + logf(s);
#pragma unroll
        for (int c = 0; c < NCLS; c++) out[g * NCLS + c] = l[c] - lse;
    }
}

extern "C" void kernel_launch(void* const* d_in, const int* in_sizes, int n_in,
                              void* d_out, int out_size, void* d_ws, size_t ws_size,
                              hipStream_t stream) {
    const float* x    = (const float*)d_in[0];
    const int*   ei   = (const int*)d_in[1];   // [2, N_EDGES]
    const int*   batch= (const int*)d_in[2];   // [N_NODES], sorted
    const float* W1a  = (const float*)d_in[3];
    const float* b1a  = (const float*)d_in[4];
    const float* W1b  = (const float*)d_in[5];
    const float* b1b  = (const float*)d_in[6];
    const float* W2a  = (const float*)d_in[7];
    const float* b2a  = (const float*)d_in[8];
    const float* W2b  = (const float*)d_in[9];
    const float* b2b  = (const float*)d_in[10];
    const float* Wfc  = (const float*)d_in[11];
    const float* bfc  = (const float*)d_in[12];
    float* out = (float*)d_out;

    // workspace layout (4-byte units), ~24 MB
    float* ws      = (float*)d_ws;
    float* xw1     = ws;                                   // N_NODES*16
    float* h1w     = xw1 + (size_t)N_NODES * F1;           // N_NODES*8
    int*   pairs   = (int*)(h1w + (size_t)N_NODES * F2);   // NBUK*CAPB = 1801728
    int*   srcs    = pairs + (size_t)NBUK * CAPB;          // NBUK*CAPB
    int*   np_g    = srcs + (size_t)NBUK * CAPB;           // NBUK*NPW = 100487
    int*   gcursor = np_g + (size_t)NBUK * NPW + 9;        // 512   (memset)
    int*   ticket  = gcursor + 512;                        // 16    (memset)
    float* gsum    = (float*)(ticket + 16);                // 512   (memset)
    float* gcnt    = gsum + NGRAPH * F2;                   // 64    (memset)

    // one tiny memset: gcursor + ticket + gsum + gcnt adjacent
    hipMemsetAsync(gcursor, 0, (512 + 16 + NGRAPH * F2 + NGRAPH) * sizeof(int),
                   stream);

    xpart_k<<<NBUK, 256, 0, stream>>>(x, W1a, xw1, ei, gcursor, pairs);
    sortgin1_k<<<NBUK, 256, 0, stream>>>(xw1, pairs, gcursor,
                                         b1a, W1b, b1b, W2a,
                                         h1w, srcs, np_g);
    gin2pf_k<<<NBUK, 256, 0, stream>>>(h1w, np_g, srcs,
                                       b2a, W2b, b2b, batch,
                                       gsum, gcnt, ticket, Wfc, bfc, out);
}

// Round 11
// 178.061 us; speedup vs baseline: 1.0868x; 1.0868x over previous
//
#include <hip/hip_runtime.h>
#include <math.h>

#define N_NODES 100000
#define N_EDGES 1600000
#define F0 32
#define F1 16
#define F2 8
#define NCLS 6
#define NGRAPH 64

#define BSH  8         // bucket = 256 nodes (power of 2 -> exact split)
#define BSZ  256       // nodes per bucket
#define NBUK 391       // ceil(100000/256)
#define CAPB 4608      // edge cap per bucket region (mean 4092, sigma 64 -> +8 sigma)
#define EPB  4093      // edges per xpart chunk: ceil(1600000/391)
#define NPW  257       // np_g stride per bucket

// ========== kernel 1: fused node-transform (x@W1a) + edge partition ==========
__global__ __launch_bounds__(256) void xpart_k(
    const float* __restrict__ x, const float* __restrict__ W1a,
    float* __restrict__ xw1, const int* __restrict__ ei,
    int* __restrict__ gcursor, int* __restrict__ pairs) {
    __shared__ float sW[F0 * F1];
    __shared__ int hist[512];
    __shared__ int cur[512];
    __shared__ int sdst[EPB];
    int t = threadIdx.x, c = blockIdx.x;
    for (int i = t; i < F0 * F1; i += 256) sW[i] = W1a[i];
    hist[t] = 0; hist[t + 256] = 0;
    __syncthreads();

    // --- stage dst + chunk histogram ---
    int base = c * EPB, eend = min(base + EPB, N_EDGES);
    for (int i = base + t; i < eend; i += 256) {
        int d = ei[N_EDGES + i];
        sdst[i - base] = d;
        atomicAdd(&hist[d >> BSH], 1);
    }

    // --- node projection (independent work, overlaps hist latency) ---
    int n = c * 256 + t;
    if (n < N_NODES) {
        const float4* xp = reinterpret_cast<const float4*>(x) + n * (F0 / 4);
        float xi[F0];
#pragma unroll
        for (int q = 0; q < F0 / 4; q++) {
            float4 v = xp[q];
            xi[4*q] = v.x; xi[4*q+1] = v.y; xi[4*q+2] = v.z; xi[4*q+3] = v.w;
        }
        float o[F1];
#pragma unroll
        for (int j = 0; j < F1; j++) {
            float s = 0.0f;
#pragma unroll
            for (int k = 0; k < F0; k++) s += xi[k] * sW[k * F1 + j];
            o[j] = s;
        }
        float4* op = reinterpret_cast<float4*>(xw1) + n * (F1 / 4);
        op[0] = make_float4(o[0],  o[1],  o[2],  o[3]);
        op[1] = make_float4(o[4],  o[5],  o[6],  o[7]);
        op[2] = make_float4(o[8],  o[9],  o[10], o[11]);
        op[3] = make_float4(o[12], o[13], o[14], o[15]);
    }
    __syncthreads();

    // --- reserve contiguous sub-range per bucket (strided: NBUK > 256) ---
    for (int b = t; b < 512; b += 256) {
        int cnt = (b < NBUK) ? hist[b] : 0;
        cur[b] = b * CAPB + (cnt ? atomicAdd(&gcursor[b], cnt) : 0);
    }
    __syncthreads();

    // --- scatter packed (dl<<17 | src) into bucket regions (guarded) ---
    for (int i = base + t; i < eend; i += 256) {
        int s = ei[i];
        int d = sdst[i - base];
        int b = d >> BSH;
        int pos = atomicAdd(&cur[b], 1);
        if (pos < (b + 1) * CAPB)                 // overflow guard (~never taken)
            pairs[pos] = ((d & (BSZ - 1)) << 17) | s;
    }
}

#define ACC16(P) { float4 q0 = (P)[0], q1 = (P)[1], q2 = (P)[2], q3 = (P)[3]; \
    acc[0] += q0.x;  acc[1] += q0.y;  acc[2]  += q0.z;  acc[3]  += q0.w;      \
    acc[4] += q1.x;  acc[5] += q1.y;  acc[6]  += q1.z;  acc[7]  += q1.w;      \
    acc[8] += q2.x;  acc[9] += q2.y;  acc[10] += q2.z;  acc[11] += q2.w;      \
    acc[12] += q3.x; acc[13] += q3.y; acc[14] += q3.z;  acc[15] += q3.w; }

// ===== kernel 2: per-bucket counting sort (LDS) + gin1, 2 lanes per node =====
// 512 threads: t<256 run the sort bookkeeping; gather uses lane-pairs per node
// (doubles occupancy, halves per-thread serial gather chain -> latency-bound fix)
__global__ __launch_bounds__(512) void sortgin1_k(
    const float* __restrict__ xw1, const int* __restrict__ pairs,
    const int* __restrict__ gcursor,
    const float* __restrict__ b1a, const float* __restrict__ W1b,
    const float* __restrict__ b1b, const float* __restrict__ W2a,
    float* __restrict__ h1w, int* __restrict__ srcs,
    int* __restrict__ np_g) {
    __shared__ int hist[256];
    __shared__ int sbuf[2][256];
    __shared__ int cur[256];
    __shared__ int np[BSZ + 1];
    __shared__ int srcs_l[CAPB];
    __shared__ float sW1b[F1 * F1];
    __shared__ float sW2a[F1 * F2];
    __shared__ float sb1a[F1], sb1b[F1];
    int t = threadIdx.x, b = blockIdx.x;
    if (t < F1 * F1) sW1b[t] = W1b[t];
    if (t < F1 * F2) sW2a[t] = W2a[t];
    if (t < F1) { sb1a[t] = b1a[t]; sb1b[t] = b1b[t]; }
    if (t < 256) hist[t] = 0;
    __syncthreads();

    int cnt = min(gcursor[b], CAPB);
    int pb = b * CAPB;
    for (int i = t; i < cnt; i += 512)
        atomicAdd(&hist[pairs[pb + i] >> 17], 1);
    __syncthreads();
    if (t < 256) sbuf[0][t] = hist[t];
    __syncthreads();
    int cb = 0;
    for (int off = 1; off < 256; off <<= 1) {
        if (t < 256) {
            int v = sbuf[cb][t];
            if (t >= off) v += sbuf[cb][t - off];
            sbuf[cb ^ 1][t] = v;
        }
        cb ^= 1;
        __syncthreads();
    }
    if (t < 256) {
        int excl = sbuf[cb][t] - hist[t];
        np[t] = excl;
        cur[t] = excl;
        np_g[b * NPW + t] = excl;
        if (t == 0) { np[BSZ] = cnt; np_g[b * NPW + BSZ] = cnt; }
    }
    __syncthreads();
    for (int i = t; i < cnt; i += 512) {
        int p = pairs[pb + i];
        int pos = atomicAdd(&cur[p >> 17], 1);
        int s = p & 0x1FFFF;
        srcs_l[pos] = s;             // consumed by gin1 below (no global round-trip)
        srcs[pb + pos] = s;          // persisted for gin2 (bucket-local write)
    }
    __syncthreads();

    // ---- gather: lane pair (2s, 2s+1) splits node s's edges ----
    int slot = t >> 1, h = t & 1;
    int n = b * BSZ + slot;
    if (n < N_NODES) {
        float acc[F1];
#pragma unroll
        for (int k = 0; k < F1; k++) acc[k] = 0.0f;
        const float4* X = reinterpret_cast<const float4*>(xw1);
        int e  = np[slot] + h;
        int e1 = np[slot + 1];
        for (; e + 6 < e1; e += 8) {           // 4 rows in flight per lane
            const float4* p0 = X + srcs_l[e + 0] * 4;
            const float4* p1 = X + srcs_l[e + 2] * 4;
            const float4* p2 = X + srcs_l[e + 4] * 4;
            const float4* p3 = X + srcs_l[e + 6] * 4;
            ACC16(p0); ACC16(p1); ACC16(p2); ACC16(p3);
        }
        for (; e < e1; e += 2) { const float4* p0 = X + srcs_l[e] * 4; ACC16(p0); }
        if (h == 0) { const float4* pn = X + n * 4; ACC16(pn); }   // self term once

        // pair-combine: lanes 2s/2s+1 are wave-internal
#pragma unroll
        for (int k = 0; k < F1; k++) acc[k] += __shfl_xor(acc[k], 1);

        if (h == 0) {
            float u[F1];
#pragma unroll
            for (int k = 0; k < F1; k++) u[k] = fmaxf(acc[k] + sb1a[k], 0.0f);
            float hh[F1];
#pragma unroll
            for (int j = 0; j < F1; j++) {
                float s = sb1b[j];
#pragma unroll
                for (int k = 0; k < F1; k++) s += u[k] * sW1b[k * F1 + j];
                hh[j] = fmaxf(s, 0.0f);        // relu∘relu = relu
            }
            float o[F2];
#pragma unroll
            for (int j = 0; j < F2; j++) {
                float s = 0.0f;
#pragma unroll
                for (int k = 0; k < F1; k++) s += hh[k] * sW2a[k * F2 + j];
                o[j] = s;
            }
            float4* hp = reinterpret_cast<float4*>(h1w) + n * 2;
            hp[0] = make_float4(o[0], o[1], o[2], o[3]);
            hp[1] = make_float4(o[4], o[5], o[6], o[7]);
        }
    }
}

#define ACC8(P) { float4 q0 = (P)[0], q1 = (P)[1];                        \
    acc[0] += q0.x; acc[1] += q0.y; acc[2] += q0.z; acc[3] += q0.w;       \
    acc[4] += q1.x; acc[5] += q1.y; acc[6] += q1.z; acc[7] += q1.w; }

// ==== kernel 3: layer-2 gather (2 lanes/node) + MLP2 + fused mean-pool ====
// 782 blocks x 256 threads, 128 nodes per block -> 2x thread count vs r10
__global__ __launch_bounds__(256) void gin2pool_k(
    const float* __restrict__ h1w, const int* __restrict__ np_g,
    const int* __restrict__ srcs, const float* __restrict__ b2a,
    const float* __restrict__ W2b, const float* __restrict__ b2b,
    const int* __restrict__ batch, float* __restrict__ gsum,
    float* __restrict__ gcnt) {
    __shared__ float sW2b[F2 * F2];
    __shared__ float sb2a[F2];
    __shared__ float sb2b[F2];
    __shared__ float ls[NGRAPH * F2];   // 512 > blockDim -> strided loops (r5 lesson)
    __shared__ float lc[NGRAPH];
    int t = threadIdx.x;
    if (t < F2 * F2) sW2b[t] = W2b[t];
    if (t < F2) { sb2a[t] = b2a[t]; sb2b[t] = b2b[t]; }
    for (int i = t; i < NGRAPH * F2; i += 256) ls[i] = 0.0f;
    if (t < NGRAPH) lc[t] = 0.0f;
    __syncthreads();

    int slot = t >> 1, h = t & 1;
    int n = blockIdx.x * 128 + slot;
    if (n < N_NODES) {
        int b  = n >> BSH;
        int sl = n & (BSZ - 1);
        int pb = b * CAPB;
        float acc[F2];
#pragma unroll
        for (int k = 0; k < F2; k++) acc[k] = 0.0f;
        const float4* H = reinterpret_cast<const float4*>(h1w);
        int e  = pb + np_g[b * NPW + sl] + h;
        int e1 = pb + np_g[b * NPW + sl + 1];
        for (; e + 6 < e1; e += 8) {
            const float4* p0 = H + srcs[e + 0] * 2;
            const float4* p1 = H + srcs[e + 2] * 2;
            const float4* p2 = H + srcs[e + 4] * 2;
            const float4* p3 = H + srcs[e + 6] * 2;
            ACC8(p0); ACC8(p1); ACC8(p2); ACC8(p3);
        }
        for (; e < e1; e += 2) { const float4* p0 = H + srcs[e] * 2; ACC8(p0); }
        if (h == 0) { const float4* pn = H + n * 2; ACC8(pn); }    // self term once

#pragma unroll
        for (int k = 0; k < F2; k++) acc[k] += __shfl_xor(acc[k], 1);

        if (h == 0) {
            float u[F2];
#pragma unroll
            for (int k = 0; k < F2; k++) u[k] = fmaxf(acc[k] + sb2a[k], 0.0f);
            float v[F2];
#pragma unroll
            for (int j = 0; j < F2; j++) {
                float s = sb2b[j];
#pragma unroll
                for (int k = 0; k < F2; k++) s += u[k] * sW2b[k * F2 + j];
                v[j] = fmaxf(s, 0.0f);
            }
            int g = batch[n];
#pragma unroll
            for (int j = 0; j < F2; j++) atomicAdd(&ls[g * F2 + j], v[j]);
            atomicAdd(&lc[g], 1.0f);
        }
    }
    __syncthreads();
    for (int i = t; i < NGRAPH * F2; i += 256)
        if (ls[i] != 0.0f) atomicAdd(&gsum[i], ls[i]);
    if (t < NGRAPH && lc[t] != 0.0f) atomicAdd(&gcnt[t], lc[t]);
}

// ---------------- final: pooled -> FC -> log_softmax ----------------
__global__ void final_k(const float* __restrict__ gsum,
                        const float* __restrict__ gcnt,
                        const float* __restrict__ Wfc, const float* __restrict__ bfc,
                        float* __restrict__ out) {
    int g = threadIdx.x;
    if (g >= NGRAPH) return;
    float cnt = fmaxf(gcnt[g], 1.0f);
    float p[F2];
#pragma unroll
    for (int f = 0; f < F2; f++) p[f] = gsum[g * F2 + f] / cnt;
    float l[NCLS];
#pragma unroll
    for (int c = 0; c < NCLS; c++) {
        float s = bfc[c];
#pragma unroll
        for (int f = 0; f < F2; f++) s += p[f] * Wfc[f * NCLS + c];
        l[c] = s;
    }
    float m = -INFINITY;
#pragma unroll
    for (int c = 0; c < NCLS; c++) m = fmaxf(m, l[c]);
    float s = 0.0f;
#pragma unroll
    for (int c = 0; c < NCLS; c++) s += expf(l[c] - m);
    float lse = m + logf(s);
#pragma unroll
    for (int c = 0; c < NCLS; c++) out[g * NCLS + c] = l[c] - lse;
}

extern "C" void kernel_launch(void* const* d_in, const int* in_sizes, int n_in,
                              void* d_out, int out_size, void* d_ws, size_t ws_size,
                              hipStream_t stream) {
    const float* x    = (const float*)d_in[0];
    const int*   ei   = (const int*)d_in[1];   // [2, N_EDGES]
    const int*   batch= (const int*)d_in[2];   // [N_NODES], sorted
    const float* W1a  = (const float*)d_in[3];
    const float* b1a  = (const float*)d_in[4];
    const float* W1b  = (const float*)d_in[5];
    const float* b1b  = (const float*)d_in[6];
    const float* W2a  = (const float*)d_in[7];
    const float* b2a  = (const float*)d_in[8];
    const float* W2b  = (const float*)d_in[9];
    const float* b2b  = (const float*)d_in[10];
    const float* Wfc  = (const float*)d_in[11];
    const float* bfc  = (const float*)d_in[12];
    float* out = (float*)d_out;

    // workspace layout (4-byte units), ~24 MB
    float* ws      = (float*)d_ws;
    float* xw1     = ws;                                   // N_NODES*16
    float* h1w     = xw1 + (size_t)N_NODES * F1;           // N_NODES*8
    int*   pairs   = (int*)(h1w + (size_t)N_NODES * F2);   // NBUK*CAPB = 1801728
    int*   srcs    = pairs + (size_t)NBUK * CAPB;          // NBUK*CAPB
    int*   np_g    = srcs + (size_t)NBUK * CAPB;           // NBUK*NPW = 100487
    int*   gcursor = np_g + (size_t)NBUK * NPW + 9;        // 512   (memset)
    float* gsum    = (float*)(gcursor + 512);              // 512   (memset)
    float* gcnt    = gsum + NGRAPH * F2;                   // 64    (memset)

    // one tiny memset: gcursor + gsum + gcnt adjacent
    hipMemsetAsync(gcursor, 0, (512 + NGRAPH * F2 + NGRAPH) * sizeof(int), stream);

    xpart_k<<<NBUK, 256, 0, stream>>>(x, W1a, xw1, ei, gcursor, pairs);
    sortgin1_k<<<NBUK, 512, 0, stream>>>(xw1, pairs, gcursor,
                                         b1a, W1b, b1b, W2a,
                                         h1w, srcs, np_g);
    gin2pool_k<<<(N_NODES + 127) / 128, 256, 0, stream>>>(h1w, np_g, srcs,
                                                          b2a, W2b, b2b, batch,
                                                          gsum, gcnt);
    final_k<<<1, 64, 0, stream>>>(gsum, gcnt, Wfc, bfc, out);
}